// Round 1
// baseline (22587.735 us; speedup 1.0000x reference)
//
#include <hip/hip_runtime.h>

#define TSEQ 8192
#define DH   2048
#define DCAT 4096
#define ROWS 8      // hidden rows per seq workgroup (2048 / 256 WGs)
#define R3   16     // time rows per out-projection workgroup

// ---------------------------------------------------------------------------
// Kernel 1: sentinel-init rows 1..8191 of d_out (used as the h exchange buf).
// Valid h values are sigmoid outputs (sign bit 0); sentinel -1.0f has sign 1.
// Must run every launch (harness does not re-poison between replays).
// ---------------------------------------------------------------------------
__global__ void init_sentinel_kernel(float* __restrict__ out) {
  const long long n4 = ((long long)(TSEQ - 1) * DH) / 4;  // rows 1..8191
  float4* p = (float4*)(out + DH);
  float4 s;
  s.x = s.y = s.z = s.w = -1.0f;
  const long long stride = (long long)gridDim.x * blockDim.x;
  for (long long i = (long long)blockIdx.x * blockDim.x + threadIdx.x; i < n4;
       i += stride)
    p[i] = s;
}

// ---------------------------------------------------------------------------
// Kernel 2: persistent sequential RNN. 256 WGs x 256 threads.
// WG g owns hidden rows [8g, 8g+8). W_h rows live in VGPRs (128 f32/thread).
// Threads 0..127 (waves 0,1) handle the x half (caption), threads 128..255
// (waves 2,3) handle the h half (spin on agent-scope loads of d_out row t-1).
// Column ownership: thread i owns col pairs {q*256 + 2i, +1} for q=0..7,
// so each 8B atomic load is lane-contiguous (fully coalesced per instr).
// ---------------------------------------------------------------------------
__global__ __launch_bounds__(256, 2) void seq_kernel(
    const float* __restrict__ features, const float* __restrict__ caption,
    const float* __restrict__ W_h, const float* __restrict__ b_h,
    float* __restrict__ out) {
  const int tid  = threadIdx.x;
  const int i    = tid & 127;   // index within half
  const int part = tid >> 7;    // 0 = x half, 1 = h half
  const int rbase = blockIdx.x * ROWS;
  const int lane = tid & 63;
  const int wid  = tid >> 6;

  // --- load this WG's weight slice into registers (one time) ---
  float w[ROWS][16];
#pragma unroll
  for (int r = 0; r < ROWS; ++r) {
    const float* wrow = W_h + (long long)(rbase + r) * DCAT + part * DH;
#pragma unroll
    for (int q = 0; q < 8; ++q) {
      float2 wv = *(const float2*)(wrow + q * 256 + i * 2);
      w[r][2 * q]     = wv.x;
      w[r][2 * q + 1] = wv.y;
    }
  }

  __shared__ float red[4][ROWS];

  for (int t = 1; t < TSEQ; ++t) {
    float a[16];
    if (part == 0) {
      // x contribution: caption[t-1] (plain cached loads; no dependency)
      const float* xrow = caption + (long long)(t - 1) * DH;
#pragma unroll
      for (int q = 0; q < 8; ++q) {
        float2 xv = *(const float2*)(xrow + q * 256 + i * 2);
        a[2 * q]     = xv.x;
        a[2 * q + 1] = xv.y;
      }
    } else if (t == 1) {
      // h0 = features (input, no wait)
#pragma unroll
      for (int q = 0; q < 8; ++q) {
        float2 xv = *(const float2*)(features + q * 256 + i * 2);
        a[2 * q]     = xv.x;
        a[2 * q + 1] = xv.y;
      }
    } else {
      // spin on h_{t-1}: agent-scope (LLC-coherent) 8B loads, sign-bit flag
      const unsigned long long* hrow =
          (const unsigned long long*)(out + (long long)(t - 1) * DH);
      unsigned long long v[8];
      for (;;) {
        unsigned long long m = 0ull;
#pragma unroll
        for (int q = 0; q < 8; ++q) {
          v[q] = __hip_atomic_load(hrow + q * 128 + i, __ATOMIC_RELAXED,
                                   __HIP_MEMORY_SCOPE_AGENT);
          m |= v[q];
        }
        if ((m & 0x8000000080000000ull) == 0ull) break;
        __builtin_amdgcn_s_sleep(1);
      }
#pragma unroll
      for (int q = 0; q < 8; ++q) {
        a[2 * q]     = __uint_as_float((unsigned int)v[q]);
        a[2 * q + 1] = __uint_as_float((unsigned int)(v[q] >> 32));
      }
    }

    // --- per-thread partial dot products for the 8 owned rows ---
    float acc[ROWS];
#pragma unroll
    for (int r = 0; r < ROWS; ++r) acc[r] = 0.0f;
#pragma unroll
    for (int j = 0; j < 16; ++j) {
#pragma unroll
      for (int r = 0; r < ROWS; ++r) acc[r] += w[r][j] * a[j];
    }

    // --- folded wave reduction: 8 values over 64 lanes in 10 shuffles ---
    float vv[8];
#pragma unroll
    for (int r = 0; r < ROWS; ++r) vv[r] = acc[r];
    {  // s=0, bit=1, keep 4
      const bool up = lane & 1;
#pragma unroll
      for (int j = 0; j < 4; ++j) {
        float send  = up ? vv[j] : vv[j + 4];
        float other = __shfl_xor(send, 1, 64);
        vv[j] = (up ? vv[j + 4] : vv[j]) + other;
      }
    }
    {  // s=1, bit=2, keep 2
      const bool up = lane & 2;
#pragma unroll
      for (int j = 0; j < 2; ++j) {
        float send  = up ? vv[j] : vv[j + 2];
        float other = __shfl_xor(send, 2, 64);
        vv[j] = (up ? vv[j + 2] : vv[j]) + other;
      }
    }
    {  // s=2, bit=4, keep 1
      const bool up = lane & 4;
      float send  = up ? vv[0] : vv[1];
      float other = __shfl_xor(send, 4, 64);
      vv[0] = (up ? vv[1] : vv[0]) + other;
    }
    float v = vv[0];
    v += __shfl_xor(v, 8, 64);
    v += __shfl_xor(v, 16, 64);
    v += __shfl_xor(v, 32, 64);
    if (lane < 8) {
      const int row = ((lane & 1) << 2) | (lane & 2) | ((lane >> 2) & 1);
      red[wid][row] = v;
    }
    __syncthreads();

    if (tid < ROWS) {
      float z = red[0][tid] + red[1][tid] + red[2][tid] + red[3][tid] +
                b_h[rbase + tid];
      float h = 1.0f / (1.0f + __expf(-z));
      __hip_atomic_store((unsigned int*)(out + (long long)t * DH + rbase + tid),
                         __float_as_uint(h), __ATOMIC_RELAXED,
                         __HIP_MEMORY_SCOPE_AGENT);
    }
    __syncthreads();
  }
}

// ---------------------------------------------------------------------------
// Kernel 3: output projection, IN PLACE on d_out.
// WG owns 16 full time-rows: stages h rows into LDS first, then overwrites
// the same rows with y = sigmoid(W_o h + b_o). Row 0 := caption[0].
// ---------------------------------------------------------------------------
__global__ __launch_bounds__(256, 1) void out_kernel(
    float* __restrict__ out, const float* __restrict__ W_o,
    const float* __restrict__ b_o, const float* __restrict__ caption) {
  __shared__ float hs[R3][DH];     // 128 KiB
  __shared__ float ws[64][68];     // 17 KiB, +4 pad: conflict-spread b128 reads
  const int tid  = threadIdx.x;
  const int lane = tid & 63;
  const int wv   = tid >> 6;       // wave id -> rows wv*4 .. wv*4+3
  const int t0   = blockIdx.x * R3;

  // stage h rows (these are the pre-overwrite contents of d_out)
  for (int idx = tid; idx < R3 * (DH / 4); idx += 256) {
    const int row = idx >> 9;      // 512 float4 per row
    const int c4  = idx & 511;
    float4 v = *(const float4*)(out + (long long)(t0 + row) * DH + c4 * 4);
    *(float4*)&hs[row][c4 * 4] = v;
  }
  __syncthreads();

  for (int o0 = 0; o0 < DH; o0 += 64) {
    float acc0 = 0.f, acc1 = 0.f, acc2 = 0.f, acc3 = 0.f;
    for (int k0 = 0; k0 < DH; k0 += 64) {
      __syncthreads();  // protect ws against previous iteration's readers
#pragma unroll
      for (int it = 0; it < 4; ++it) {
        const int fidx = tid + it * 256;  // 1024 float4 in the 64x64 chunk
        const int row = fidx >> 4;
        const int c4  = fidx & 15;
        float4 v = *(const float4*)(W_o + (long long)(o0 + row) * DH + k0 +
                                    c4 * 4);
        *(float4*)&ws[row][c4 * 4] = v;
      }
      __syncthreads();
#pragma unroll
      for (int k = 0; k < 64; k += 4) {
        const float4 wq  = *(const float4*)&ws[lane][k];
        const float4 h0v = *(const float4*)&hs[wv * 4 + 0][k0 + k];
        const float4 h1v = *(const float4*)&hs[wv * 4 + 1][k0 + k];
        const float4 h2v = *(const float4*)&hs[wv * 4 + 2][k0 + k];
        const float4 h3v = *(const float4*)&hs[wv * 4 + 3][k0 + k];
        acc0 += wq.x * h0v.x + wq.y * h0v.y + wq.z * h0v.z + wq.w * h0v.w;
        acc1 += wq.x * h1v.x + wq.y * h1v.y + wq.z * h1v.z + wq.w * h1v.w;
        acc2 += wq.x * h2v.x + wq.y * h2v.y + wq.z * h2v.z + wq.w * h2v.w;
        acc3 += wq.x * h3v.x + wq.y * h3v.y + wq.z * h3v.z + wq.w * h3v.w;
      }
    }
    const int o   = o0 + lane;
    const float bo = b_o[o];
    float y[4] = {acc0, acc1, acc2, acc3};
#pragma unroll
    for (int r = 0; r < 4; ++r) {
      const int trow = t0 + wv * 4 + r;
      float val = 1.0f / (1.0f + __expf(-(y[r] + bo)));
      if (trow == 0) val = caption[o];  // output[0] = caption[0]
      out[(long long)trow * DH + o] = val;
    }
  }
}

// ---------------------------------------------------------------------------
extern "C" void kernel_launch(void* const* d_in, const int* in_sizes, int n_in,
                              void* d_out, int out_size, void* d_ws,
                              size_t ws_size, hipStream_t stream) {
  const float* features = (const float*)d_in[0];
  const float* caption  = (const float*)d_in[1];
  const float* W_h      = (const float*)d_in[2];
  const float* b_h      = (const float*)d_in[3];
  const float* W_o      = (const float*)d_in[4];
  const float* b_o      = (const float*)d_in[5];
  float* out = (float*)d_out;

  hipLaunchKernelGGL(init_sentinel_kernel, dim3(2048), dim3(256), 0, stream,
                     out);
  hipLaunchKernelGGL(seq_kernel, dim3(DH / ROWS), dim3(256), 0, stream,
                     features, caption, W_h, b_h, out);
  hipLaunchKernelGGL(out_kernel, dim3(TSEQ / R3), dim3(256), 0, stream, out,
                     W_o, b_o, caption);
}

// Round 2
// 21023.140 us; speedup vs baseline: 1.0744x; 1.0744x over previous
//
#include <hip/hip_runtime.h>

#define TSEQ 8192
#define DH   2048
#define DCAT 4096
#define ROWS 8      // hidden rows per seq workgroup (2048 / 256 WGs)
#define R3   16     // time rows per out-projection workgroup

// ---------------------------------------------------------------------------
// Kernel 1: sentinel-init rows 1..8191 of d_out (used as the h exchange buf).
// Valid h values are sigmoid outputs (sign bit 0); sentinel -1.0f has sign 1.
// Must run every launch (harness does not re-poison between replays).
// ---------------------------------------------------------------------------
__global__ void init_sentinel_kernel(float* __restrict__ out) {
  const long long n4 = ((long long)(TSEQ - 1) * DH) / 4;  // rows 1..8191
  float4* p = (float4*)(out + DH);
  float4 s;
  s.x = s.y = s.z = s.w = -1.0f;
  const long long stride = (long long)gridDim.x * blockDim.x;
  for (long long i = (long long)blockIdx.x * blockDim.x + threadIdx.x; i < n4;
       i += stride)
    p[i] = s;
}

// ---------------------------------------------------------------------------
// Kernel 2: persistent sequential RNN. 256 WGs x 512 threads.
// WG g owns hidden rows [8g, 8g+8). Per-thread weight slice is w[8][8] =
// 64 f32 -> guaranteed VGPR-resident (round-1 failure mode: 256-thread
// version needed 128 regs of weights, compiler re-loaded from memory every
// step, ~32 MB/step of L2/LLC traffic on the serial critical path).
// Threads 0..255 (waves 0-3) handle the x half (caption), threads 256..511
// (waves 4-7) handle the h half (spin on agent-scope loads of d_out row t-1).
// Column ownership: thread i owns col pairs {q*512 + 2i, +1} for q=0..3,
// so each 8B load is lane-contiguous (fully coalesced per instruction).
// ---------------------------------------------------------------------------
__global__ __launch_bounds__(512, 1) void seq_kernel(
    const float* __restrict__ features, const float* __restrict__ caption,
    const float* __restrict__ W_h, const float* __restrict__ b_h,
    float* __restrict__ out) {
  const int tid  = threadIdx.x;
  const int i    = tid & 255;   // index within half
  const int part = tid >> 8;    // 0 = x half, 1 = h half
  const int rbase = blockIdx.x * ROWS;
  const int lane = tid & 63;
  const int wid  = tid >> 6;    // 0..7

  // --- load this WG's weight slice into registers (one time) ---
  float w[ROWS][8];
#pragma unroll
  for (int r = 0; r < ROWS; ++r) {
    const float* wrow = W_h + (long long)(rbase + r) * DCAT + part * DH;
#pragma unroll
    for (int q = 0; q < 4; ++q) {
      float2 wv = *(const float2*)(wrow + q * 512 + i * 2);
      w[r][2 * q]     = wv.x;
      w[r][2 * q + 1] = wv.y;
    }
  }
  const float bias = (tid < ROWS) ? b_h[rbase + tid] : 0.0f;

  __shared__ float red[8][ROWS];

  for (int t = 1; t < TSEQ; ++t) {
    float a[8];
    if (part == 0) {
      // x contribution: caption[t-1] (plain cached loads; no dependency)
      const float* xrow = caption + (long long)(t - 1) * DH;
#pragma unroll
      for (int q = 0; q < 4; ++q) {
        float2 xv = *(const float2*)(xrow + q * 512 + i * 2);
        a[2 * q]     = xv.x;
        a[2 * q + 1] = xv.y;
      }
    } else if (t == 1) {
      // h0 = features (input, no wait)
#pragma unroll
      for (int q = 0; q < 4; ++q) {
        float2 xv = *(const float2*)(features + q * 512 + i * 2);
        a[2 * q]     = xv.x;
        a[2 * q + 1] = xv.y;
      }
    } else {
      // spin on h_{t-1}: agent-scope (LLC-coherent) 8B loads, sign-bit flag
      const unsigned long long* hrow =
          (const unsigned long long*)(out + (long long)(t - 1) * DH);
      unsigned long long v[4];
      for (;;) {
        unsigned long long m = 0ull;
#pragma unroll
        for (int q = 0; q < 4; ++q) {
          v[q] = __hip_atomic_load(hrow + q * 256 + i, __ATOMIC_RELAXED,
                                   __HIP_MEMORY_SCOPE_AGENT);
          m |= v[q];
        }
        if ((m & 0x8000000080000000ull) == 0ull) break;
        __builtin_amdgcn_s_sleep(1);
      }
#pragma unroll
      for (int q = 0; q < 4; ++q) {
        a[2 * q]     = __uint_as_float((unsigned int)v[q]);
        a[2 * q + 1] = __uint_as_float((unsigned int)(v[q] >> 32));
      }
    }

    // --- per-thread partial dot products for the 8 owned rows ---
    float acc[ROWS];
#pragma unroll
    for (int r = 0; r < ROWS; ++r) acc[r] = 0.0f;
#pragma unroll
    for (int j = 0; j < 8; ++j) {
#pragma unroll
      for (int r = 0; r < ROWS; ++r) acc[r] += w[r][j] * a[j];
    }

    // --- folded wave reduction: 8 values over 64 lanes in 9 shuffles ---
    float vv[8];
#pragma unroll
    for (int r = 0; r < ROWS; ++r) vv[r] = acc[r];
    {  // s=0, bit=1, keep 4
      const bool up = lane & 1;
#pragma unroll
      for (int j = 0; j < 4; ++j) {
        float send  = up ? vv[j] : vv[j + 4];
        float other = __shfl_xor(send, 1, 64);
        vv[j] = (up ? vv[j + 4] : vv[j]) + other;
      }
    }
    {  // s=1, bit=2, keep 2
      const bool up = lane & 2;
#pragma unroll
      for (int j = 0; j < 2; ++j) {
        float send  = up ? vv[j] : vv[j + 2];
        float other = __shfl_xor(send, 2, 64);
        vv[j] = (up ? vv[j + 2] : vv[j]) + other;
      }
    }
    {  // s=2, bit=4, keep 1
      const bool up = lane & 4;
      float send  = up ? vv[0] : vv[1];
      float other = __shfl_xor(send, 4, 64);
      vv[0] = (up ? vv[1] : vv[0]) + other;
    }
    float v = vv[0];
    v += __shfl_xor(v, 8, 64);
    v += __shfl_xor(v, 16, 64);
    v += __shfl_xor(v, 32, 64);
    if (lane < 8) {
      const int row = ((lane & 1) << 2) | (lane & 2) | ((lane >> 2) & 1);
      red[wid][row] = v;
    }
    __syncthreads();

    if (tid < ROWS) {
      float z = bias;
#pragma unroll
      for (int wv2 = 0; wv2 < 8; ++wv2) z += red[wv2][tid];
      float h = 1.0f / (1.0f + __expf(-z));
      __hip_atomic_store((unsigned int*)(out + (long long)t * DH + rbase + tid),
                         __float_as_uint(h), __ATOMIC_RELAXED,
                         __HIP_MEMORY_SCOPE_AGENT);
    }
    __syncthreads();
  }
}

// ---------------------------------------------------------------------------
// Kernel 3: output projection, IN PLACE on d_out.
// WG owns 16 full time-rows: stages h rows into LDS first, then overwrites
// the same rows with y = sigmoid(W_o h + b_o). Row 0 := caption[0].
// ---------------------------------------------------------------------------
__global__ __launch_bounds__(256, 1) void out_kernel(
    float* __restrict__ out, const float* __restrict__ W_o,
    const float* __restrict__ b_o, const float* __restrict__ caption) {
  __shared__ float hs[R3][DH];     // 128 KiB
  __shared__ float ws[64][68];     // 17 KiB, +4 pad: conflict-spread b128 reads
  const int tid  = threadIdx.x;
  const int lane = tid & 63;
  const int wv   = tid >> 6;       // wave id -> rows wv*4 .. wv*4+3
  const int t0   = blockIdx.x * R3;

  // stage h rows (these are the pre-overwrite contents of d_out)
  for (int idx = tid; idx < R3 * (DH / 4); idx += 256) {
    const int row = idx >> 9;      // 512 float4 per row
    const int c4  = idx & 511;
    float4 v = *(const float4*)(out + (long long)(t0 + row) * DH + c4 * 4);
    *(float4*)&hs[row][c4 * 4] = v;
  }
  __syncthreads();

  for (int o0 = 0; o0 < DH; o0 += 64) {
    float acc0 = 0.f, acc1 = 0.f, acc2 = 0.f, acc3 = 0.f;
    for (int k0 = 0; k0 < DH; k0 += 64) {
      __syncthreads();  // protect ws against previous iteration's readers
#pragma unroll
      for (int it = 0; it < 4; ++it) {
        const int fidx = tid + it * 256;  // 1024 float4 in the 64x64 chunk
        const int row = fidx >> 4;
        const int c4  = fidx & 15;
        float4 v = *(const float4*)(W_o + (long long)(o0 + row) * DH + k0 +
                                    c4 * 4);
        *(float4*)&ws[row][c4 * 4] = v;
      }
      __syncthreads();
#pragma unroll
      for (int k = 0; k < 64; k += 4) {
        const float4 wq  = *(const float4*)&ws[lane][k];
        const float4 h0v = *(const float4*)&hs[wv * 4 + 0][k0 + k];
        const float4 h1v = *(const float4*)&hs[wv * 4 + 1][k0 + k];
        const float4 h2v = *(const float4*)&hs[wv * 4 + 2][k0 + k];
        const float4 h3v = *(const float4*)&hs[wv * 4 + 3][k0 + k];
        acc0 += wq.x * h0v.x + wq.y * h0v.y + wq.z * h0v.z + wq.w * h0v.w;
        acc1 += wq.x * h1v.x + wq.y * h1v.y + wq.z * h1v.z + wq.w * h1v.w;
        acc2 += wq.x * h2v.x + wq.y * h2v.y + wq.z * h2v.z + wq.w * h2v.w;
        acc3 += wq.x * h3v.x + wq.y * h3v.y + wq.z * h3v.z + wq.w * h3v.w;
      }
    }
    const int o   = o0 + lane;
    const float bo = b_o[o];
    float y[4] = {acc0, acc1, acc2, acc3};
#pragma unroll
    for (int r = 0; r < 4; ++r) {
      const int trow = t0 + wv * 4 + r;
      float val = 1.0f / (1.0f + __expf(-(y[r] + bo)));
      if (trow == 0) val = caption[o];  // output[0] = caption[0]
      out[(long long)trow * DH + o] = val;
    }
  }
}

// ---------------------------------------------------------------------------
extern "C" void kernel_launch(void* const* d_in, const int* in_sizes, int n_in,
                              void* d_out, int out_size, void* d_ws,
                              size_t ws_size, hipStream_t stream) {
  const float* features = (const float*)d_in[0];
  const float* caption  = (const float*)d_in[1];
  const float* W_h      = (const float*)d_in[2];
  const float* b_h      = (const float*)d_in[3];
  const float* W_o      = (const float*)d_in[4];
  const float* b_o      = (const float*)d_in[5];
  float* out = (float*)d_out;

  hipLaunchKernelGGL(init_sentinel_kernel, dim3(2048), dim3(256), 0, stream,
                     out);
  hipLaunchKernelGGL(seq_kernel, dim3(DH / ROWS), dim3(512), 0, stream,
                     features, caption, W_h, b_h, out);
  hipLaunchKernelGGL(out_kernel, dim3(TSEQ / R3), dim3(256), 0, stream, out,
                     W_o, b_o, caption);
}

// Round 4
// 13436.836 us; speedup vs baseline: 1.6810x; 1.5646x over previous
//
#include <hip/hip_runtime.h>

#define TSEQ 8192
#define DH   2048
#define DCAT 4096
#define ROWS 8      // hidden rows per seq workgroup (2048 / 256 WGs)
#define R3   32     // time rows per out-projection workgroup

typedef __attribute__((ext_vector_type(8))) short bf16x8;
typedef __attribute__((ext_vector_type(4))) float f32x4;

__device__ inline short f2bf(float f) {  // RNE float->bf16
  unsigned int u = __float_as_uint(f);
  unsigned int r = (u + 0x7fffu + ((u >> 16) & 1u)) >> 16;
  return (short)r;
}

// ---------------------------------------------------------------------------
// Kernel 1: sentinel-init rows 1..8191 of d_out (h exchange buffer).
// Valid h values are sigmoid outputs (sign bit 0); sentinel -1.0f has sign 1.
// ---------------------------------------------------------------------------
__global__ void init_sentinel_kernel(float* __restrict__ out) {
  const long long n4 = ((long long)(TSEQ - 1) * DH) / 4;  // rows 1..8191
  float4* p = (float4*)(out + DH);
  float4 s;
  s.x = s.y = s.z = s.w = -1.0f;
  const long long stride = (long long)gridDim.x * blockDim.x;
  for (long long i = (long long)blockIdx.x * blockDim.x + threadIdx.x; i < n4;
       i += stride)
    p[i] = s;
}

// ---------------------------------------------------------------------------
// Kernel 2: persistent sequential RNN. 256 WGs x 512 threads.
// WG g owns hidden rows [8g, 8g+8). Weights live in LDS (128 KB slice),
// per-thread 64-float blocks, 16B-granule XOR swizzle (gi ^ (tid&7)) so the
// per-step 2x ds_read_b128 per row hit the 8-dword/bank floor. ds_reads are
// issued BEFORE the h-spin so LDS latency hides under the LLC round trip.
// (Rounds 1-3 failure mode: compiler refused to keep a 64-f32 weight slice
// VGPR-resident, re-fetching from global every step on the critical path.)
// x half (threads 0..255) prefetches caption rows one step ahead; h half
// spins on agent-scope loads of d_out row t-1 (sign-bit ready flag).
// ---------------------------------------------------------------------------
__global__ __launch_bounds__(512, 1) void seq_kernel(
    const float* __restrict__ features, const float* __restrict__ caption,
    const float* __restrict__ W_h, const float* __restrict__ b_h,
    float* __restrict__ out) {
  const int tid  = threadIdx.x;
  const int i    = tid & 255;   // index within half
  const int part = tid >> 8;    // 0 = x half, 1 = h half
  const int rbase = blockIdx.x * ROWS;
  const int lane = tid & 63;
  const int wid  = tid >> 6;    // 0..7

  __shared__ float wlds[512 * 64];   // exactly 128 KiB
  __shared__ float red[8][ROWS];

  // --- one-time: stage this WG's weight slice into per-thread LDS blocks ---
  // thread's logical block: w[r][j], j=0..7 <-> W col (part*DH + (j>>1)*512
  // + 2i + (j&1)).  granule gi = (r*8+j)>>2, physical granule = gi^(tid&7).
  const int swz = (tid & 7) << 2;    // float-unit granule swizzle
#pragma unroll
  for (int r = 0; r < ROWS; ++r) {
    const float* wrow = W_h + (long long)(rbase + r) * DCAT + part * DH;
#pragma unroll
    for (int q = 0; q < 4; ++q) {
      float2 wv = *(const float2*)(wrow + q * 512 + i * 2);
      const int lofs = r * 8 + q * 2;  // logical float offset, (lofs&3)in{0,2}
      *(float2*)&wlds[tid * 64 + (((lofs & ~3) ^ swz) | (lofs & 3))] = wv;
    }
  }
  const float bias = (tid < ROWS) ? b_h[rbase + tid] : 0.0f;
  __syncthreads();

  // x-half: preload caption row 0 (consumed at t=1)
  float an[8];
  if (part == 0) {
#pragma unroll
    for (int q = 0; q < 4; ++q) {
      float2 xv = *(const float2*)(caption + q * 512 + i * 2);
      an[2 * q]     = xv.x;
      an[2 * q + 1] = xv.y;
    }
  }

  for (int t = 1; t < TSEQ; ++t) {
    // --- issue weight ds_reads first; latency hides under the spin ---
    float4 wr0[ROWS], wr1[ROWS];
#pragma unroll
    for (int r = 0; r < ROWS; ++r) {
      wr0[r] = *(const float4*)&wlds[tid * 64 + ((r * 8) ^ swz)];
      wr1[r] = *(const float4*)&wlds[tid * 64 + ((r * 8 + 4) ^ swz)];
    }

    float a[8];
    if (part == 0) {
      // consume prefetched row t-1; issue prefetch of row t (for t+1).
#pragma unroll
      for (int j = 0; j < 8; ++j) a[j] = an[j];
      const float* xn = caption + (long long)t * DH;
#pragma unroll
      for (int q = 0; q < 4; ++q) {
        float2 xv = *(const float2*)(xn + q * 512 + i * 2);
        an[2 * q]     = xv.x;
        an[2 * q + 1] = xv.y;
      }
    } else if (t == 1) {
      // h0 = features (input, no wait)
#pragma unroll
      for (int q = 0; q < 4; ++q) {
        float2 xv = *(const float2*)(features + q * 512 + i * 2);
        a[2 * q]     = xv.x;
        a[2 * q + 1] = xv.y;
      }
    } else {
      // spin on h_{t-1}: agent-scope (LLC-coherent) 8B loads, sign-bit flag
      const unsigned long long* hrow =
          (const unsigned long long*)(out + (long long)(t - 1) * DH);
      unsigned long long v[4];
      for (;;) {
        unsigned long long m = 0ull;
#pragma unroll
        for (int q = 0; q < 4; ++q) {
          v[q] = __hip_atomic_load(hrow + q * 256 + i, __ATOMIC_RELAXED,
                                   __HIP_MEMORY_SCOPE_AGENT);
          m |= v[q];
        }
        if ((m & 0x8000000080000000ull) == 0ull) break;
        __builtin_amdgcn_s_sleep(1);
      }
#pragma unroll
      for (int q = 0; q < 4; ++q) {
        a[2 * q]     = __uint_as_float((unsigned int)v[q]);
        a[2 * q + 1] = __uint_as_float((unsigned int)(v[q] >> 32));
      }
    }

    // --- per-thread partial dot products for the 8 owned rows ---
    float acc[ROWS];
#pragma unroll
    for (int r = 0; r < ROWS; ++r) {
      acc[r] = wr0[r].x * a[0] + wr0[r].y * a[1] + wr0[r].z * a[2] +
               wr0[r].w * a[3] + wr1[r].x * a[4] + wr1[r].y * a[5] +
               wr1[r].z * a[6] + wr1[r].w * a[7];
    }

    // --- folded wave reduction: 8 values over 64 lanes in 9 shuffles ---
    float vv[8];
#pragma unroll
    for (int r = 0; r < ROWS; ++r) vv[r] = acc[r];
    {  // s=0, bit=1, keep 4
      const bool up = lane & 1;
#pragma unroll
      for (int j = 0; j < 4; ++j) {
        float send  = up ? vv[j] : vv[j + 4];
        float other = __shfl_xor(send, 1, 64);
        vv[j] = (up ? vv[j + 4] : vv[j]) + other;
      }
    }
    {  // s=1, bit=2, keep 2
      const bool up = lane & 2;
#pragma unroll
      for (int j = 0; j < 2; ++j) {
        float send  = up ? vv[j] : vv[j + 2];
        float other = __shfl_xor(send, 2, 64);
        vv[j] = (up ? vv[j + 2] : vv[j]) + other;
      }
    }
    {  // s=2, bit=4, keep 1
      const bool up = lane & 4;
      float send  = up ? vv[0] : vv[1];
      float other = __shfl_xor(send, 4, 64);
      vv[0] = (up ? vv[1] : vv[0]) + other;
    }
    float v = vv[0];
    v += __shfl_xor(v, 8, 64);
    v += __shfl_xor(v, 16, 64);
    v += __shfl_xor(v, 32, 64);
    if (lane < 8) {
      const int row = ((lane & 1) << 2) | (lane & 2) | ((lane >> 2) & 1);
      red[wid][row] = v;
    }
    __syncthreads();

    if (tid < ROWS) {
      float z = bias;
#pragma unroll
      for (int wv2 = 0; wv2 < 8; ++wv2) z += red[wv2][tid];
      float h = 1.0f / (1.0f + __expf(-z));
      __hip_atomic_store((unsigned int*)(out + (long long)t * DH + rbase + tid),
                         __float_as_uint(h), __ATOMIC_RELAXED,
                         __HIP_MEMORY_SCOPE_AGENT);
    }
    __syncthreads();
  }
}

// ---------------------------------------------------------------------------
// Kernel 3: output projection via bf16 MFMA, IN PLACE on d_out.
// WG owns R3=32 full time-rows: stages them as bf16 in LDS (exactly 128 KB,
// XOR-swizzled 16B granules: phys = logical ^ ((row&7)<<3) in short units —
// round-3 bug was a 1032-short row stride for 2048-element rows: rows
// overlapped and half of every dot product read the wrong time-row).
// 4 waves x (2 m-tiles x 32 n-tiles); W_o B-frags converted f32->bf16 on
// the fly. Row 0 := caption[0].
// ---------------------------------------------------------------------------
__global__ __launch_bounds__(256, 1) void out_mfma_kernel(
    float* __restrict__ out, const float* __restrict__ W_o,
    const float* __restrict__ b_o, const float* __restrict__ caption) {
  __shared__ __align__(16) short hs[R3 * 2048];  // exactly 128 KiB
  const int tid  = threadIdx.x;
  const int lane = tid & 63;
  const int wv   = tid >> 6;       // wave id: n-cols [wv*512, wv*512+512)
  const long long t0 = (long long)blockIdx.x * R3;
  const int r16  = lane & 15;
  const int kgrp = (lane >> 4) * 8;  // k-octet base within 32-wide k-step

  // stage h rows (pre-overwrite contents of d_out) as bf16, swizzled
  for (int idx = tid; idx < R3 * 256; idx += 256) {
    const int row = idx >> 8;      // 256 float8 per row
    const int c8  = idx & 255;
    const float* src = out + (t0 + row) * DH + c8 * 8;
    float4 va = *(const float4*)src;
    float4 vb = *(const float4*)(src + 4);
    bf16x8 h8;
    h8[0] = f2bf(va.x); h8[1] = f2bf(va.y); h8[2] = f2bf(va.z); h8[3] = f2bf(va.w);
    h8[4] = f2bf(vb.x); h8[5] = f2bf(vb.y); h8[6] = f2bf(vb.z); h8[7] = f2bf(vb.w);
    *(bf16x8*)&hs[row * 2048 + ((c8 * 8) ^ ((row & 7) << 3))] = h8;
  }
  __syncthreads();

  const int sw0 = (r16 & 7) << 3;  // same for row r16 and row 16+r16

  for (int half = 0; half < 4; ++half) {   // 4 chunks of 8 n-tiles per wave
    const int n0 = wv * 512 + half * 128;
    f32x4 acc0[8], acc1[8];
#pragma unroll
    for (int j = 0; j < 8; ++j) {
      acc0[j] = (f32x4){0.f, 0.f, 0.f, 0.f};
      acc1[j] = (f32x4){0.f, 0.f, 0.f, 0.f};
    }
    for (int k0 = 0; k0 < DH; k0 += 32) {
      const int kofs = (k0 + kgrp) ^ sw0;
      bf16x8 a0 = *(const bf16x8*)&hs[r16 * 2048 + kofs];
      bf16x8 a1 = *(const bf16x8*)&hs[(16 + r16) * 2048 + kofs];
#pragma unroll
      for (int j = 0; j < 8; ++j) {
        const float* wp =
            W_o + (long long)(n0 + j * 16 + r16) * DH + k0 + kgrp;
        float4 wa = *(const float4*)wp;
        float4 wb = *(const float4*)(wp + 4);
        bf16x8 bfr;
        bfr[0] = f2bf(wa.x); bfr[1] = f2bf(wa.y);
        bfr[2] = f2bf(wa.z); bfr[3] = f2bf(wa.w);
        bfr[4] = f2bf(wb.x); bfr[5] = f2bf(wb.y);
        bfr[6] = f2bf(wb.z); bfr[7] = f2bf(wb.w);
        acc0[j] = __builtin_amdgcn_mfma_f32_16x16x32_bf16(a0, bfr, acc0[j], 0, 0, 0);
        acc1[j] = __builtin_amdgcn_mfma_f32_16x16x32_bf16(a1, bfr, acc1[j], 0, 0, 0);
      }
    }
    // epilogue: bias + sigmoid + in-place store (D: col=lane&15, row=(lane>>4)*4+r)
#pragma unroll
    for (int j = 0; j < 8; ++j) {
      const int n = n0 + j * 16 + r16;
      const float bo = b_o[n];
#pragma unroll
      for (int r = 0; r < 4; ++r) {
        const long long row0 = t0 + (lane >> 4) * 4 + r;
        float v0 = 1.0f / (1.0f + __expf(-(acc0[j][r] + bo)));
        if (row0 == 0) v0 = caption[n];  // output[0] = caption[0]
        out[row0 * DH + n] = v0;
        const long long row1 = t0 + 16 + (lane >> 4) * 4 + r;
        float v1 = 1.0f / (1.0f + __expf(-(acc1[j][r] + bo)));
        out[row1 * DH + n] = v1;
      }
    }
  }
}

// ---------------------------------------------------------------------------
extern "C" void kernel_launch(void* const* d_in, const int* in_sizes, int n_in,
                              void* d_out, int out_size, void* d_ws,
                              size_t ws_size, hipStream_t stream) {
  const float* features = (const float*)d_in[0];
  const float* caption  = (const float*)d_in[1];
  const float* W_h      = (const float*)d_in[2];
  const float* b_h      = (const float*)d_in[3];
  const float* W_o      = (const float*)d_in[4];
  const float* b_o      = (const float*)d_in[5];
  float* out = (float*)d_out;

  hipLaunchKernelGGL(init_sentinel_kernel, dim3(2048), dim3(256), 0, stream,
                     out);
  hipLaunchKernelGGL(seq_kernel, dim3(DH / ROWS), dim3(512), 0, stream,
                     features, caption, W_h, b_h, out);
  hipLaunchKernelGGL(out_mfma_kernel, dim3(TSEQ / R3), dim3(256), 0, stream,
                     out, W_o, b_o, caption);
}